// Round 3
// baseline (215.116 us; speedup 1.0000x reference)
//
#include <hip/hip_runtime.h>
#include <hip/hip_bf16.h>
#include <math.h>

// SelfAttention: out = softmax(mask(q k^T)/32) v, q=xWq^T k=xWk^T v=xWv^T
// N=4096 tokens, E=1024. bf16 MFMA compute, fp32 accumulate.
// R3: T3-minimum 2-phase LDS double-buffer (stage-next -> compute-current ->
//     single syncthreads drain) + T1 bijective XCD swizzle on all GEMM grids.

typedef __attribute__((ext_vector_type(8))) __bf16 bf16x8;
typedef __attribute__((ext_vector_type(4))) __bf16 bf16x4;
typedef __attribute__((ext_vector_type(4))) float f32x4;

__device__ __forceinline__ void gload_lds16(const void* g, void* l) {
  __builtin_amdgcn_global_load_lds(
      (__attribute__((address_space(1))) void*)(g),
      (__attribute__((address_space(3))) void*)(l), 16, 0, 0);
}

// One launch converts x, Wq, Wk, Wv to bf16. Blocks partitioned by range.
__global__ __launch_bounds__(256) void cvt_all(const float* __restrict__ x,
                                               const float* __restrict__ wq,
                                               const float* __restrict__ wk,
                                               const float* __restrict__ wv,
                                               __bf16* __restrict__ xb,
                                               __bf16* __restrict__ wqb,
                                               __bf16* __restrict__ wkb,
                                               __bf16* __restrict__ wvb) {
  int b = blockIdx.x;
  const float* in;
  __bf16* out;
  int base;
  if (b < 4096)      { in = x;  out = xb;  base = b; }
  else if (b < 5120) { in = wq; out = wqb; base = b - 4096; }
  else if (b < 6144) { in = wk; out = wkb; base = b - 5120; }
  else               { in = wv; out = wvb; base = b - 6144; }
  int i = base * 256 + threadIdx.x;
  float4 f = ((const float4*)in)[i];
  bf16x4 o;
  o[0] = (__bf16)f.x; o[1] = (__bf16)f.y; o[2] = (__bf16)f.z; o[3] = (__bf16)f.w;
  ((bf16x4*)out)[i] = o;
}

// ---- shared GEMM structure: B^T-form, tile 128x128, BK=64, 4 waves,
// ---- LDS double-buffered (2 x 32KB = 64KB), T3-minimum schedule.

#define GEMM_PROLOGUE_DB()                                \
  __shared__ __bf16 lsA[2][128 * 64];                     \
  __shared__ __bf16 lsB[2][128 * 64];                     \
  const int tid = threadIdx.x;                            \
  const int lane = tid & 63;                              \
  const int w = tid >> 6;                                 \
  const int wr = w >> 1, wc = w & 1;                      \
  const int hi = lane >> 4;                               \
  const int lo = lane & 15;                               \
  f32x4 acc[4][4] = {};

// Issue 8 x 16B global_load_lds per thread into buffer `buf` for K-offset k0.
#define GEMM_STAGE(buf, Aptr, lda, Bptr, ldb, k0)                          \
  {                                                                        \
    _Pragma("unroll") for (int i = 0; i < 4; ++i) {                        \
      int c = i * 256 + tid;                                               \
      int r = c >> 3, cv = c & 7;                                          \
      gload_lds16((Aptr) + (row0 + r) * (long)(lda) + (k0) + cv * 8,       \
                  lsA[buf] + (i * 256 + w * 64) * 8);                      \
    }                                                                      \
    _Pragma("unroll") for (int i = 0; i < 4; ++i) {                        \
      int c = i * 256 + tid;                                               \
      int r = c >> 3, cv = c & 7;                                          \
      gload_lds16((Bptr) + (col0 + r) * (long)(ldb) + (k0) + cv * 8,       \
                  lsB[buf] + (i * 256 + w * 64) * 8);                      \
    }                                                                      \
  }

// ds_read fragments from buffer `buf` and run the 32-MFMA cluster (BK=64).
#define GEMM_COMPUTE(buf)                                                  \
  _Pragma("unroll") for (int kk = 0; kk < 64; kk += 32) {                  \
    bf16x8 af[4], bfr[4];                                                  \
    _Pragma("unroll") for (int m = 0; m < 4; ++m)                          \
      af[m] = *(const bf16x8*)(lsA[buf] + (wr * 64 + m * 16 + lo) * 64 + kk + hi * 8); \
    _Pragma("unroll") for (int n = 0; n < 4; ++n)                          \
      bfr[n] = *(const bf16x8*)(lsB[buf] + (wc * 64 + n * 16 + lo) * 64 + kk + hi * 8); \
    _Pragma("unroll") for (int m = 0; m < 4; ++m)                          \
      _Pragma("unroll") for (int n = 0; n < 4; ++n)                        \
        acc[m][n] = __builtin_amdgcn_mfma_f32_16x16x32_bf16(af[m], bfr[n], acc[m][n], 0, 0, 0); \
  }

// T3-minimum main loop: prologue-stage, then {stage-next, compute-current,
// one syncthreads (vmcnt0+lgkmcnt0+barrier)} per K-step. Race-free: reads of
// buf complete before the barrier; writes to buf^1 land before the barrier;
// next iter's overwrite of buf happens only after all waves passed it.
#define GEMM_MAINLOOP(Aptr, lda, Bptr, ldb, kstart, kend)                  \
  GEMM_STAGE(0, Aptr, lda, Bptr, ldb, kstart);                             \
  __syncthreads();                                                         \
  {                                                                        \
    int cur = 0;                                                           \
    for (int k0 = (kstart); k0 < (kend); k0 += 64) {                       \
      if (k0 + 64 < (kend)) GEMM_STAGE(cur ^ 1, Aptr, lda, Bptr, ldb, k0 + 64); \
      GEMM_COMPUTE(cur);                                                   \
      __syncthreads();                                                     \
      cur ^= 1;                                                            \
    }                                                                      \
  }

// sim GEMM: C[r][c] = sum_k A[r][k]*B[c][k], fp32 store. Grid: 1024 blocks.
// Work decomposition: wid -> (by=wid>>5, bx=wid&31); XCD-swizzled.
__global__ __launch_bounds__(256) void gemm_bt_f32(const __bf16* __restrict__ A, int lda,
                                                   const __bf16* __restrict__ B, int ldb,
                                                   float* __restrict__ C, int ldc, int K) {
  const int raw = blockIdx.x;
  const int wid = (raw & 7) * 128 + (raw >> 3);  // nwg=1024, bijective
  const long row0 = (long)(wid >> 5) * 128;
  const long col0 = (long)(wid & 31) * 128;
  GEMM_PROLOGUE_DB();
  GEMM_MAINLOOP(A, lda, B, ldb, 0, K);
#pragma unroll
  for (int m = 0; m < 4; ++m)
#pragma unroll
    for (int n = 0; n < 4; ++n)
#pragma unroll
      for (int i = 0; i < 4; ++i) {
        long r = row0 + wr * 64 + m * 16 + hi * 4 + i;
        long cc = col0 + wc * 64 + n * 16 + lo;
        C[r * (long)ldc + cc] = acc[m][n][i];
      }
}

// Fused QKV: z=0 -> q, z=1 -> k, z=2 -> v stored TRANSPOSED (vT [1024][4096]).
// All: M=4096 tokens, N=1024 features, K=1024. Grid: 768 blocks.
__global__ __launch_bounds__(256) void qkv_gemm(const __bf16* __restrict__ xb,
                                                const __bf16* __restrict__ wq,
                                                const __bf16* __restrict__ wk,
                                                const __bf16* __restrict__ wv,
                                                __bf16* __restrict__ qb,
                                                __bf16* __restrict__ kb,
                                                __bf16* __restrict__ vtb) {
  const int raw = blockIdx.x;
  const int wid = (raw & 7) * 96 + (raw >> 3);   // nwg=768, bijective
  const int z = wid >> 8;
  const int r2 = wid & 255;
  const long row0 = (long)(r2 >> 3) * 128;       // token tile
  const long col0 = (long)(r2 & 7) * 128;        // feature tile
  const __bf16* Bw = (z == 0) ? wq : (z == 1) ? wk : wv;
  GEMM_PROLOGUE_DB();
  GEMM_MAINLOOP(xb, 1024, Bw, 1024, 0, 1024);
#pragma unroll
  for (int m = 0; m < 4; ++m)
#pragma unroll
    for (int n = 0; n < 4; ++n)
#pragma unroll
      for (int i = 0; i < 4; ++i) {
        long r = row0 + wr * 64 + m * 16 + hi * 4 + i;   // token index
        long cc = col0 + wc * 64 + n * 16 + lo;          // feature index
        __bf16 v = (__bf16)acc[m][n][i];
        if (z == 0)      qb[r * 1024 + cc] = v;
        else if (z == 1) kb[r * 1024 + cc] = v;
        else             vtb[cc * 4096 + r] = v;         // transposed store
      }
}

// PV split-K x2: z=0 -> K [0,2048) into out (fp32), z=1 -> K [2048,4096) into p1.
// A = attn (bf16, ld 8192), B = vT (bf16, ld 4096). Grid: 512 blocks.
__global__ __launch_bounds__(256) void pv_gemm(const __bf16* __restrict__ attn,
                                               const __bf16* __restrict__ vt,
                                               float* __restrict__ out,
                                               float* __restrict__ p1) {
  const int raw = blockIdx.x;
  const int wid = (raw & 7) * 64 + (raw >> 3);   // nwg=512, bijective
  const int z = wid >> 8;
  const int r2 = wid & 255;
  const long row0 = (long)(r2 >> 3) * 128;
  const long col0 = (long)(r2 & 7) * 128;
  float* C = z ? p1 : out;
  const int kbase = z * 2048;
  GEMM_PROLOGUE_DB();
  GEMM_MAINLOOP(attn, 8192, vt, 4096, kbase, kbase + 2048);
#pragma unroll
  for (int m = 0; m < 4; ++m)
#pragma unroll
    for (int n = 0; n < 4; ++n)
#pragma unroll
      for (int i = 0; i < 4; ++i) {
        long r = row0 + wr * 64 + m * 16 + hi * 4 + i;
        long cc = col0 + wc * 64 + n * 16 + lo;
        C[r * 1024 + cc] = acc[m][n][i];
      }
}

__global__ __launch_bounds__(256) void reduce_add(float* __restrict__ out,
                                                  const float* __restrict__ p1) {
  int i = blockIdx.x * 256 + threadIdx.x;  // 1,048,576 float4s
  float4 a = ((const float4*)out)[i];
  float4 b = ((const float4*)p1)[i];
  a.x += b.x; a.y += b.y; a.z += b.z; a.w += b.w;
  ((float4*)out)[i] = a;
}

// One block per row: mask (-1e20 where mask==0), stable softmax of row/32,
// write attn as bf16 IN-PLACE over the fp32 row (attn ld = 8192 bf16 elems).
__global__ __launch_bounds__(256) void softmax_rows(float* __restrict__ sim,
                                                    const int* __restrict__ mask) {
  const int row = blockIdx.x;
  float* rp = sim + (size_t)row * 4096;
  const int4* mrow = (const int4*)(mask + (size_t)row * 4096);
  const int tid = threadIdx.x;

  float vals[16];
  float lmax = -INFINITY;
#pragma unroll
  for (int j = 0; j < 4; ++j) {
    float4 f = ((const float4*)rp)[tid + 256 * j];
    int4 mm = mrow[tid + 256 * j];
    f.x = mm.x ? f.x : -1e20f;
    f.y = mm.y ? f.y : -1e20f;
    f.z = mm.z ? f.z : -1e20f;
    f.w = mm.w ? f.w : -1e20f;
    vals[4 * j + 0] = f.x; vals[4 * j + 1] = f.y;
    vals[4 * j + 2] = f.z; vals[4 * j + 3] = f.w;
    lmax = fmaxf(lmax, fmaxf(fmaxf(f.x, f.y), fmaxf(f.z, f.w)));
  }
#pragma unroll
  for (int off = 32; off; off >>= 1) lmax = fmaxf(lmax, __shfl_xor(lmax, off));
  __shared__ float red[4];
  __shared__ float bro[2];
  if ((tid & 63) == 0) red[tid >> 6] = lmax;
  __syncthreads();
  if (tid == 0) bro[0] = fmaxf(fmaxf(red[0], red[1]), fmaxf(red[2], red[3]));
  __syncthreads();
  const float m = bro[0];

  float e[16];
  float lsum = 0.f;
#pragma unroll
  for (int j = 0; j < 16; ++j) {
    e[j] = __expf((vals[j] - m) * 0.03125f);  // /sqrt(1024)
    lsum += e[j];
  }
#pragma unroll
  for (int off = 32; off; off >>= 1) lsum += __shfl_xor(lsum, off);
  if ((tid & 63) == 0) red[tid >> 6] = lsum;
  __syncthreads();
  if (tid == 0) bro[1] = red[0] + red[1] + red[2] + red[3];
  __syncthreads();
  const float inv = 1.0f / bro[1];

  __bf16* op = (__bf16*)rp;
#pragma unroll
  for (int j = 0; j < 4; ++j) {
    bf16x4 o;
    o[0] = (__bf16)(e[4 * j + 0] * inv);
    o[1] = (__bf16)(e[4 * j + 1] * inv);
    o[2] = (__bf16)(e[4 * j + 2] * inv);
    o[3] = (__bf16)(e[4 * j + 3] * inv);
    ((bf16x4*)op)[tid + 256 * j] = o;
  }
}

extern "C" void kernel_launch(void* const* d_in, const int* in_sizes, int n_in,
                              void* d_out, int out_size, void* d_ws, size_t ws_size,
                              hipStream_t stream) {
  const float* x = (const float*)d_in[0];
  const int* mask = (const int*)d_in[1];
  const float* Wq = (const float*)d_in[2];
  const float* Wk = (const float*)d_in[3];
  const float* Wv = (const float*)d_in[4];
  float* out = (float*)d_out;

  // Workspace layout (102 MB):
  // [0,2M)   Wq bf16   [2M,4M)  Wk bf16   [4M,6M)  Wv bf16
  // [6M,14M) x bf16    [14M,22M) q bf16   [22M,30M) k bf16
  // [30M,38M) vT bf16  [38M,102M) sim fp32 (attn bf16 in-place, ld 8192)
  // PV-time reuse: [0,16M) = split-K partial p1 (W/x region dead by then).
  char* ws = (char*)d_ws;
  __bf16* wqb = (__bf16*)(ws);
  __bf16* wkb = (__bf16*)(ws + (2ull << 20));
  __bf16* wvb = (__bf16*)(ws + (4ull << 20));
  __bf16* xb  = (__bf16*)(ws + (6ull << 20));
  __bf16* qb  = (__bf16*)(ws + (14ull << 20));
  __bf16* kb  = (__bf16*)(ws + (22ull << 20));
  __bf16* vtb = (__bf16*)(ws + (30ull << 20));
  float*  sim = (float*)(ws + (38ull << 20));
  float*  p1  = (float*)(ws);  // 16 MB, reused after q/k/x dead

  cvt_all<<<7168, 256, 0, stream>>>(x, Wq, Wk, Wv, xb, wqb, wkb, wvb);

  dim3 blk(256);
  // q,k,vT in one dispatch: 768 blocks (XCD-swizzled inside)
  qkv_gemm<<<768, blk, 0, stream>>>(xb, wqb, wkb, wvb, qb, kb, vtb);
  // sim[i][j] = sum_e q[i,e] k[j,e]  (M=N=4096), raw fp32, 1024 blocks
  gemm_bt_f32<<<1024, blk, 0, stream>>>(qb, 1024, kb, 1024, sim, 4096, 1024);
  // masked softmax, attn bf16 in-place (ld 8192)
  softmax_rows<<<4096, 256, 0, stream>>>(sim, mask);
  // out[i][j] = sum_k attn[i,k] vT[j,k]; split-K x2 (z=0 -> out, z=1 -> p1)
  pv_gemm<<<512, blk, 0, stream>>>((const __bf16*)sim, vtb, out, p1);
  reduce_add<<<4096, 256, 0, stream>>>(out, p1);
}

// Round 4
// 190.600 us; speedup vs baseline: 1.1286x; 1.1286x over previous
//
#include <hip/hip_runtime.h>
#include <hip/hip_bf16.h>
#include <math.h>

// SelfAttention: out = softmax(mask(q k^T)/32) v, q=xWq^T k=xWk^T v=xWv^T
// N=4096 tokens, E=1024. bf16 MFMA compute, fp32 accumulate.
// R4: counted-vmcnt 2-deep pipeline (inline-asm s_waitcnt vmcnt(8) + raw
//     s_barrier; never drain to 0 mid-loop) + sim stored bf16.

typedef __attribute__((ext_vector_type(8))) __bf16 bf16x8;
typedef __attribute__((ext_vector_type(4))) __bf16 bf16x4;
typedef __attribute__((ext_vector_type(4))) float f32x4;

__device__ __forceinline__ void gload_lds16(const void* g, void* l) {
  __builtin_amdgcn_global_load_lds(
      (__attribute__((address_space(1))) void*)(g),
      (__attribute__((address_space(3))) void*)(l), 16, 0, 0);
}

// Counted wait + barrier: drain to N outstanding vmem ops, then join waves.
// In-order vmcnt retire => the (issued-N) OLDEST loads have landed.
#define WAITB(N) asm volatile("s_waitcnt vmcnt(" #N ")\ns_barrier" ::: "memory")
#define BAR()    asm volatile("s_barrier" ::: "memory")

// One launch converts x, Wq, Wk, Wv to bf16. Blocks partitioned by range.
__global__ __launch_bounds__(256) void cvt_all(const float* __restrict__ x,
                                               const float* __restrict__ wq,
                                               const float* __restrict__ wk,
                                               const float* __restrict__ wv,
                                               __bf16* __restrict__ xb,
                                               __bf16* __restrict__ wqb,
                                               __bf16* __restrict__ wkb,
                                               __bf16* __restrict__ wvb) {
  int b = blockIdx.x;
  const float* in;
  __bf16* out;
  int base;
  if (b < 4096)      { in = x;  out = xb;  base = b; }
  else if (b < 5120) { in = wq; out = wqb; base = b - 4096; }
  else if (b < 6144) { in = wk; out = wkb; base = b - 5120; }
  else               { in = wv; out = wvb; base = b - 6144; }
  int i = base * 256 + threadIdx.x;
  float4 f = ((const float4*)in)[i];
  bf16x4 o;
  o[0] = (__bf16)f.x; o[1] = (__bf16)f.y; o[2] = (__bf16)f.z; o[3] = (__bf16)f.w;
  ((bf16x4*)out)[i] = o;
}

// ---- shared GEMM structure: B^T-form, tile 128x128, BK=64, 4 waves,
// ---- LDS double-buffered, 2-deep counted-vmcnt pipeline.

#define GEMM_PROLOGUE_DB()                                \
  __shared__ __bf16 lsA[2][128 * 64];                     \
  __shared__ __bf16 lsB[2][128 * 64];                     \
  const int tid = threadIdx.x;                            \
  const int lane = tid & 63;                              \
  const int w = tid >> 6;                                 \
  const int wr = w >> 1, wc = w & 1;                      \
  const int hi = lane >> 4;                               \
  const int lo = lane & 15;                               \
  f32x4 acc[4][4] = {};

// Issue 8 x 16B global_load_lds (4 A + 4 B) into buffer `buf` for K-offset k0.
#define GEMM_STAGE(buf, Aptr, lda, Bptr, ldb, k0)                          \
  {                                                                        \
    _Pragma("unroll") for (int i = 0; i < 4; ++i) {                        \
      int c = i * 256 + tid;                                               \
      int r = c >> 3, cv = c & 7;                                          \
      gload_lds16((Aptr) + (row0 + r) * (long)(lda) + (k0) + cv * 8,       \
                  lsA[buf] + (i * 256 + w * 64) * 8);                      \
    }                                                                      \
    _Pragma("unroll") for (int i = 0; i < 4; ++i) {                        \
      int c = i * 256 + tid;                                               \
      int r = c >> 3, cv = c & 7;                                          \
      gload_lds16((Bptr) + (col0 + r) * (long)(ldb) + (k0) + cv * 8,       \
                  lsB[buf] + (i * 256 + w * 64) * 8);                      \
    }                                                                      \
  }

// ds_read fragments from buffer `buf` and run the 32-MFMA cluster (BK=64).
#define GEMM_COMPUTE(buf)                                                  \
  _Pragma("unroll") for (int kk = 0; kk < 64; kk += 32) {                  \
    bf16x8 af[4], bfr[4];                                                  \
    _Pragma("unroll") for (int m = 0; m < 4; ++m)                          \
      af[m] = *(const bf16x8*)(lsA[buf] + (wr * 64 + m * 16 + lo) * 64 + kk + hi * 8); \
    _Pragma("unroll") for (int n = 0; n < 4; ++n)                          \
      bfr[n] = *(const bf16x8*)(lsB[buf] + (wc * 64 + n * 16 + lo) * 64 + kk + hi * 8); \
    _Pragma("unroll") for (int m = 0; m < 4; ++m)                          \
      _Pragma("unroll") for (int n = 0; n < 4; ++n)                        \
        acc[m][n] = __builtin_amdgcn_mfma_f32_16x16x32_bf16(af[m], bfr[n], acc[m][n], 0, 0, 0); \
  }

// 2-deep counted pipeline. Per iter: ONE counted vmcnt (8 = next tile's loads
// stay in flight) + 2 barriers. Loads issued 2 tiles ahead; each load hides
// under a full compute phase. Requires (kend-kstart)/64 >= 2.
#define GEMM_MAINLOOP_P2(Aptr, lda, Bptr, ldb, kstart, kend)               \
  GEMM_STAGE(0, Aptr, lda, Bptr, ldb, (kstart));                           \
  GEMM_STAGE(1, Aptr, lda, Bptr, ldb, (kstart) + 64);                      \
  {                                                                        \
    int cur = 0;                                                           \
    for (int k0 = (kstart); k0 < (kend); k0 += 64) {                       \
      if (k0 + 64 < (kend)) { WAITB(8); } else { WAITB(0); }               \
      GEMM_COMPUTE(cur);                                                   \
      BAR();                                                               \
      if (k0 + 128 < (kend))                                               \
        GEMM_STAGE(cur, Aptr, lda, Bptr, ldb, k0 + 128);                   \
      cur ^= 1;                                                            \
    }                                                                      \
  }

// sim GEMM: sim[r][c] = sum_k q[r,k]*k[c,k], stored BF16 (ld 4096).
// Grid: 1024 blocks, XCD-swizzled.
__global__ __launch_bounds__(256) void qk_gemm(const __bf16* __restrict__ A,
                                               const __bf16* __restrict__ B,
                                               __bf16* __restrict__ C) {
  const int raw = blockIdx.x;
  const int wid = (raw & 7) * 128 + (raw >> 3);  // nwg=1024, bijective
  const long row0 = (long)(wid >> 5) * 128;
  const long col0 = (long)(wid & 31) * 128;
  GEMM_PROLOGUE_DB();
  GEMM_MAINLOOP_P2(A, 1024, B, 1024, 0, 1024);
#pragma unroll
  for (int m = 0; m < 4; ++m)
#pragma unroll
    for (int n = 0; n < 4; ++n)
#pragma unroll
      for (int i = 0; i < 4; ++i) {
        long r = row0 + wr * 64 + m * 16 + hi * 4 + i;
        long cc = col0 + wc * 64 + n * 16 + lo;
        C[r * 4096 + cc] = (__bf16)acc[m][n][i];
      }
}

// Fused QKV: z=0 -> q, z=1 -> k, z=2 -> v stored TRANSPOSED (vT [1024][4096]).
// All: M=4096 tokens, N=1024 features, K=1024. Grid: 768 blocks.
__global__ __launch_bounds__(256) void qkv_gemm(const __bf16* __restrict__ xb,
                                                const __bf16* __restrict__ wq,
                                                const __bf16* __restrict__ wk,
                                                const __bf16* __restrict__ wv,
                                                __bf16* __restrict__ qb,
                                                __bf16* __restrict__ kb,
                                                __bf16* __restrict__ vtb) {
  const int raw = blockIdx.x;
  const int wid = (raw & 7) * 96 + (raw >> 3);   // nwg=768, bijective
  const int z = wid >> 8;
  const int r2 = wid & 255;
  const long row0 = (long)(r2 >> 3) * 128;       // token tile
  const long col0 = (long)(r2 & 7) * 128;        // feature tile
  const __bf16* Bw = (z == 0) ? wq : (z == 1) ? wk : wv;
  GEMM_PROLOGUE_DB();
  GEMM_MAINLOOP_P2(xb, 1024, Bw, 1024, 0, 1024);
#pragma unroll
  for (int m = 0; m < 4; ++m)
#pragma unroll
    for (int n = 0; n < 4; ++n)
#pragma unroll
      for (int i = 0; i < 4; ++i) {
        long r = row0 + wr * 64 + m * 16 + hi * 4 + i;   // token index
        long cc = col0 + wc * 64 + n * 16 + lo;          // feature index
        __bf16 v = (__bf16)acc[m][n][i];
        if (z == 0)      qb[r * 1024 + cc] = v;
        else if (z == 1) kb[r * 1024 + cc] = v;
        else             vtb[cc * 4096 + r] = v;         // transposed store
      }
}

// PV split-K x2: z=0 -> K [0,2048) into out (fp32), z=1 -> K [2048,4096) into p1.
// A = attn (bf16, ld 4096), B = vT (bf16, ld 4096). Grid: 512 blocks.
__global__ __launch_bounds__(256) void pv_gemm(const __bf16* __restrict__ attn,
                                               const __bf16* __restrict__ vt,
                                               float* __restrict__ out,
                                               float* __restrict__ p1) {
  const int raw = blockIdx.x;
  const int wid = (raw & 7) * 64 + (raw >> 3);   // nwg=512, bijective
  const int z = wid >> 8;
  const int r2 = wid & 255;
  const long row0 = (long)(r2 >> 3) * 128;
  const long col0 = (long)(r2 & 7) * 128;
  float* C = z ? p1 : out;
  const int kbase = z * 2048;
  GEMM_PROLOGUE_DB();
  GEMM_MAINLOOP_P2(attn, 4096, vt, 4096, kbase, kbase + 2048);
#pragma unroll
  for (int m = 0; m < 4; ++m)
#pragma unroll
    for (int n = 0; n < 4; ++n)
#pragma unroll
      for (int i = 0; i < 4; ++i) {
        long r = row0 + wr * 64 + m * 16 + hi * 4 + i;
        long cc = col0 + wc * 64 + n * 16 + lo;
        C[r * 1024 + cc] = acc[m][n][i];
      }
}

__global__ __launch_bounds__(256) void reduce_add(float* __restrict__ out,
                                                  const float* __restrict__ p1) {
  int i = blockIdx.x * 256 + threadIdx.x;  // 1,048,576 float4s
  float4 a = ((const float4*)out)[i];
  float4 b = ((const float4*)p1)[i];
  a.x += b.x; a.y += b.y; a.z += b.z; a.w += b.w;
  ((float4*)out)[i] = a;
}

// One block per row of bf16 sim (ld 4096): mask (-1e20 where mask==0), stable
// softmax of row/32, write attn bf16 IN-PLACE.
__global__ __launch_bounds__(256) void softmax_rows(__bf16* __restrict__ sim,
                                                    const int* __restrict__ mask) {
  const int row = blockIdx.x;
  __bf16* rp = sim + (size_t)row * 4096;
  const int4* mrow = (const int4*)(mask + (size_t)row * 4096);
  const int tid = threadIdx.x;

  float vals[16];
  float lmax = -INFINITY;
#pragma unroll
  for (int j = 0; j < 2; ++j) {           // two 8-elem bf16 chunks per thread
    bf16x8 s = ((const bf16x8*)rp)[tid + 256 * j];
    int4 m0 = mrow[(tid + 256 * j) * 2];
    int4 m1 = mrow[(tid + 256 * j) * 2 + 1];
    float f[8];
#pragma unroll
    for (int e = 0; e < 8; ++e) f[e] = (float)s[e];
    f[0] = m0.x ? f[0] : -1e20f;  f[1] = m0.y ? f[1] : -1e20f;
    f[2] = m0.z ? f[2] : -1e20f;  f[3] = m0.w ? f[3] : -1e20f;
    f[4] = m1.x ? f[4] : -1e20f;  f[5] = m1.y ? f[5] : -1e20f;
    f[6] = m1.z ? f[6] : -1e20f;  f[7] = m1.w ? f[7] : -1e20f;
#pragma unroll
    for (int e = 0; e < 8; ++e) {
      vals[8 * j + e] = f[e];
      lmax = fmaxf(lmax, f[e]);
    }
  }
#pragma unroll
  for (int off = 32; off; off >>= 1) lmax = fmaxf(lmax, __shfl_xor(lmax, off));
  __shared__ float red[4];
  __shared__ float bro[2];
  if ((tid & 63) == 0) red[tid >> 6] = lmax;
  __syncthreads();
  if (tid == 0) bro[0] = fmaxf(fmaxf(red[0], red[1]), fmaxf(red[2], red[3]));
  __syncthreads();
  const float m = bro[0];

  float e[16];
  float lsum = 0.f;
#pragma unroll
  for (int j = 0; j < 16; ++j) {
    e[j] = __expf((vals[j] - m) * 0.03125f);  // /sqrt(1024)
    lsum += e[j];
  }
#pragma unroll
  for (int off = 32; off; off >>= 1) lsum += __shfl_xor(lsum, off);
  if ((tid & 63) == 0) red[tid >> 6] = lsum;
  __syncthreads();
  if (tid == 0) bro[1] = red[0] + red[1] + red[2] + red[3];
  __syncthreads();
  const float inv = 1.0f / bro[1];

#pragma unroll
  for (int j = 0; j < 2; ++j) {
    bf16x8 o;
#pragma unroll
    for (int q = 0; q < 8; ++q) o[q] = (__bf16)(e[8 * j + q] * inv);
    ((bf16x8*)rp)[tid + 256 * j] = o;
  }
}

extern "C" void kernel_launch(void* const* d_in, const int* in_sizes, int n_in,
                              void* d_out, int out_size, void* d_ws, size_t ws_size,
                              hipStream_t stream) {
  const float* x = (const float*)d_in[0];
  const int* mask = (const int*)d_in[1];
  const float* Wq = (const float*)d_in[2];
  const float* Wk = (const float*)d_in[3];
  const float* Wv = (const float*)d_in[4];
  float* out = (float*)d_out;

  // Workspace layout (70 MB):
  // [0,2M)   Wq bf16   [2M,4M)  Wk bf16   [4M,6M)  Wv bf16
  // [6M,14M) x bf16    [14M,22M) q bf16   [22M,30M) k bf16
  // [30M,38M) vT bf16  [38M,70M) sim bf16 (attn bf16 in-place, ld 4096)
  // PV-time reuse: [0,16M) = split-K partial p1 (W/x region dead by then).
  char* ws = (char*)d_ws;
  __bf16* wqb = (__bf16*)(ws);
  __bf16* wkb = (__bf16*)(ws + (2ull << 20));
  __bf16* wvb = (__bf16*)(ws + (4ull << 20));
  __bf16* xb  = (__bf16*)(ws + (6ull << 20));
  __bf16* qb  = (__bf16*)(ws + (14ull << 20));
  __bf16* kb  = (__bf16*)(ws + (22ull << 20));
  __bf16* vtb = (__bf16*)(ws + (30ull << 20));
  __bf16* sim = (__bf16*)(ws + (38ull << 20));
  float*  p1  = (float*)(ws);  // 16 MB, reused after q/k/x dead

  cvt_all<<<7168, 256, 0, stream>>>(x, Wq, Wk, Wv, xb, wqb, wkb, wvb);

  dim3 blk(256);
  // q,k,vT in one dispatch: 768 blocks (XCD-swizzled inside)
  qkv_gemm<<<768, blk, 0, stream>>>(xb, wqb, wkb, wvb, qb, kb, vtb);
  // sim[i][j] = sum_e q[i,e] k[j,e]  (M=N=4096), bf16 out, 1024 blocks
  qk_gemm<<<1024, blk, 0, stream>>>(qb, kb, sim);
  // masked softmax, attn bf16 in-place (ld 4096)
  softmax_rows<<<4096, 256, 0, stream>>>(sim, mask);
  // out[i][j] = sum_k attn[i,k] vT[j,k]; split-K x2 (z=0 -> out, z=1 -> p1)
  pv_gemm<<<512, blk, 0, stream>>>(sim, vtb, out, p1);
  reduce_add<<<4096, 256, 0, stream>>>(out, p1);
}